// Round 10
// baseline (111.330 us; speedup 1.0000x reference)
//
#include <hip/hip_runtime.h>
#include <math.h>

#define DM    1024
#define DQK   128
#define BATCH 4
#define SEQ   4096
// 1/sqrt(128) * log2(e) folded into Wq/bq at wcvt time -> softmax uses exp2 directly
#define QSCALE (0.08838834764831845f * 1.4426950408889634f)
#define DEFER_THR 6.0f

typedef _Float16 f16;
typedef _Float16 f16x4 __attribute__((ext_vector_type(4)));
typedef _Float16 f16x8 __attribute__((ext_vector_type(8)));
typedef float    f32x4 __attribute__((ext_vector_type(4)));

// ---------------- W convert/transpose pre-kernel ----------------
__global__ __launch_bounds__(256) void wcvt_kernel(
    const float* __restrict__ Wq, const float* __restrict__ bq,
    const float* __restrict__ Wk, const float* __restrict__ bk,
    const float* __restrict__ Wv, const float* __restrict__ bv,
    f16* __restrict__ wt, float* __restrict__ biasf)
{
    const int sel = blockIdx.x >> 3;
    const int k0  = (blockIdx.x & 7) * 128;
    const float* W; const float* b; float sc;
    if (sel == 0)      { W = Wq; b = bq; sc = QSCALE; }
    else if (sel == 1) { W = Wk; b = bk; sc = 1.0f; }
    else               { W = Wv; b = bv; sc = 1.0f; }

    __shared__ f16 tile[128][136];

    #pragma unroll
    for (int it = 0; it < 16; ++it) {
        int flat = threadIdx.x + it * 256;
        int kk   = flat >> 5;
        int c4   = flat & 31;
        float4 w4 = *(const float4*)(W + (size_t)(k0 + kk) * DQK + c4 * 4);
        tile[kk][c4 * 4 + 0] = (f16)(w4.x * sc);
        tile[kk][c4 * 4 + 1] = (f16)(w4.y * sc);
        tile[kk][c4 * 4 + 2] = (f16)(w4.z * sc);
        tile[kk][c4 * 4 + 3] = (f16)(w4.w * sc);
    }
    __syncthreads();

    #pragma unroll
    for (int it = 0; it < 8; ++it) {
        int flat = threadIdx.x + it * 256;
        int n    = flat >> 4;
        int kc   = flat & 15;
        f16x8 v;
        #pragma unroll
        for (int i = 0; i < 8; ++i) v[i] = tile[kc * 8 + i][n];
        *(f16x8*)(wt + (size_t)(sel * 128 + n) * DM + k0 + kc * 8) = v;
    }
    if ((blockIdx.x & 7) == 0 && threadIdx.x < 128)
        biasf[sel * 128 + threadIdx.x] = b[threadIdx.x] * sc;
}

// ---------------- Fused QKV projection, f16 MFMA (unchanged) ----------------
__global__ __launch_bounds__(512, 2) void proj_kernel(
    const float* __restrict__ x, const f16* __restrict__ wt,
    const float* __restrict__ biasf,
    f16* __restrict__ qo, f16* __restrict__ ko, f16* __restrict__ vto)
{
    __shared__ __align__(16) unsigned char smem[50176];

    const int tid  = threadIdx.x;
    const int lane = tid & 63;
    const int w    = tid >> 6;
    const int c    = lane & 15;
    const int g    = lane >> 4;
    const int r0   = blockIdx.x * 64;

    const int srow = tid >> 3;
    const int skq  = tid & 7;
    const float* const xsrc  = x + (size_t)(r0 + srow) * DM + skq * 8;
    const unsigned     swoff = (unsigned)(srow * 128 + ((skq ^ (srow & 7)) * 16));

    f32x4 acc[4][3];
    #pragma unroll
    for (int rf = 0; rf < 4; ++rf)
        #pragma unroll
        for (int nf = 0; nf < 3; ++nf) acc[rf][nf] = (f32x4)0.f;

    float4 xa, xb2;
    auto gload = [&](int t) {
        const float* p = xsrc + t * 64;
        xa  = *(const float4*)p;
        xb2 = *(const float4*)(p + 4);
    };
    auto swrite = [&](int buf) {
        f16x8 h;
        h[0] = (f16)xa.x;  h[1] = (f16)xa.y;  h[2] = (f16)xa.z;  h[3] = (f16)xa.w;
        h[4] = (f16)xb2.x; h[5] = (f16)xb2.y; h[6] = (f16)xb2.z; h[7] = (f16)xb2.w;
        *(f16x8*)(smem + (unsigned)buf * 8192u + swoff) = h;
    };

    gload(0); swrite(0);
    gload(1);
    __syncthreads();

    for (int t = 0; t < 16; ++t) {
        const int cur = t & 1;
        if (t < 15) swrite(cur ^ 1);
        if (t < 14) gload(t + 2);

        f16x8 af[4][2];
        #pragma unroll
        for (int rf = 0; rf < 4; ++rf)
            #pragma unroll
            for (int ks = 0; ks < 2; ++ks)
                af[rf][ks] = *(const f16x8*)(smem + (unsigned)cur * 8192u
                    + (unsigned)((rf * 16 + c) * 128)
                    + (unsigned)((((4 * ks + g) ^ (c & 7)) * 16)));

        #pragma unroll
        for (int nf = 0; nf < 3; ++nf) {
            #pragma unroll
            for (int ks = 0; ks < 2; ++ks) {
                f16x8 bf = *(const f16x8*)(wt
                    + (size_t)(w * 48 + nf * 16 + c) * DM + t * 64 + ks * 32 + g * 8);
                #pragma unroll
                for (int rf = 0; rf < 4; ++rf)
                    acc[rf][nf] = __builtin_amdgcn_mfma_f32_16x16x32_f16(
                        af[rf][ks], bf, acc[rf][nf], 0, 0, 0);
            }
        }
        __syncthreads();
    }

    f16* const tile = (f16*)smem;
    #pragma unroll
    for (int rf = 0; rf < 4; ++rf)
        #pragma unroll
        for (int nf = 0; nf < 3; ++nf) {
            const int n  = w * 48 + nf * 16 + c;
            const float bb = biasf[n];
            #pragma unroll
            for (int r = 0; r < 4; ++r) {
                const int row = rf * 16 + 4 * g + r;
                tile[row * 392 + n] = (f16)(acc[rf][nf][r] + bb);
            }
        }
    __syncthreads();

    #pragma unroll
    for (int it = 0; it < 2; ++it) {
        const int u   = tid + it * 512;
        const int row = u >> 4;
        const int c8  = (u & 15) * 8;
        *(f16x8*)(qo + (size_t)(r0 + row) * DQK + c8) = *(const f16x8*)&tile[row * 392 + c8];
        *(f16x8*)(ko + (size_t)(r0 + row) * DQK + c8) = *(const f16x8*)&tile[row * 392 + 128 + c8];
    }
    const int gb = r0 >> 12;
    const int s0 = r0 & (SEQ - 1);
    #pragma unroll
    for (int it = 0; it < 2; ++it) {
        const int u  = tid + it * 512;
        const int d  = u >> 3;
        const int s8 = (u & 7) * 8;
        f16x8 vv;
        #pragma unroll
        for (int i = 0; i < 8; ++i) vv[i] = tile[(s8 + i) * 392 + 256 + d];
        *(f16x8*)(vto + ((size_t)gb * DQK + d) * SEQ + s0 + s8) = vv;
    }
}

// ---------------- Flash attention: r4 dataflow + in-lane P via K=16 PV MFMAs ----------------
// grid 256 x 512 thr (8 waves = wq 0..1 x wk 0..3). K,V LDS double-buffered, 1 barrier/iter.
// Swapped QK^T leaves S^T[kv=4g+r][q=16n+c] exactly in the 16x16x16 PV A-frag layout
// ([q=lane&15][kv=4*(lane>>4)+i]) -> P = in-lane cvt_pkrtz, NO bpermute, NO P-LDS.
__device__ __forceinline__ void stage16(const void* g, unsigned char* l) {
    __builtin_amdgcn_global_load_lds(
        (const __attribute__((address_space(1))) unsigned int*)g,
        (__attribute__((address_space(3))) unsigned int*)l, 16, 0, 0);
}

#define KOFF 0u        // 2 x 32 KB K double buffer
#define VOFF 65536u    // 2 x 32 KB V double buffer
#define MOFF 131072u
#define LOFF 132096u

__global__ __launch_bounds__(512, 2) void attn_kernel(
    const f16* __restrict__ qg, const f16* __restrict__ kg,
    const f16* __restrict__ vtg, float* __restrict__ out)
{
    __shared__ __align__(16) unsigned char smem[133120];

    const int tid  = threadIdx.x;
    const int lane = tid & 63;
    const int w    = tid >> 6;      // 0..7
    const int wq   = w >> 2;        // 0..1
    const int wk   = w & 3;         // 0..3
    const int c    = lane & 15;
    const int g    = lane >> 4;     // 0..3

    const int bid = blockIdx.x;
    const int xcd = bid & 7;
    const int bb  = xcd >> 1;       // batch pinned to XCD pair (K/V L2-resident)
    const int qt  = (bid >> 3) | ((xcd & 1) << 5);
    const int q0  = qt * 64;

    const f16*  qb = qg  + (size_t)bb * SEQ * DQK;
    const char* kB = (const char*)(kg  + (size_t)bb * SEQ * DQK);
    const char* vB = (const char*)(vtg + (size_t)bb * DQK * SEQ);

    // Q frags (B-operand for swapped QK^T): q = 16n + c, d = ks*32 + 8g + i
    f16x8 qf[2][4];
    {
        const f16* qr = qb + (size_t)(q0 + wq * 32) * DQK;
        #pragma unroll
        for (int n = 0; n < 2; ++n)
            #pragma unroll
            for (int ks = 0; ks < 4; ++ks)
                qf[n][ks] = *(const f16x8*)(qr + (n * 16 + c) * DQK + ks * 32 + 8 * g);
    }

    f32x4 o[2][8];   // O[q = 16n + 4g + r][d = df*16 + c]
    #pragma unroll
    for (int n = 0; n < 2; ++n)
        #pragma unroll
        for (int f = 0; f < 8; ++f) o[n][f] = (f32x4)0.f;
    float m_run[2] = {-3e38f, -3e38f};   // per q = 16n + c
    float l_run[2] = {0.f, 0.f};

    const unsigned wbase = (unsigned)w * 1024;

    auto stage_tiles = [&](int t, int pbuf) {
        const int kv0 = t * 128;
        unsigned char* kdst = smem + KOFF + (unsigned)pbuf * 32768u + wbase;
        unsigned char* vdst = smem + VOFF + (unsigned)pbuf * 32768u + wbase;
        #pragma unroll
        for (int cc = 0; cc < 4; ++cc) {
            const int j   = tid + cc * 512;
            const int row = j >> 4;
            const int col = j & 15;
            const int sw  = (col ^ (row & 7)) * 16;
            stage16(kB + (size_t)(kv0 + row) * 256 + sw, kdst + cc * 8192);
            stage16(vB + (size_t)row * 8192 + (size_t)kv0 * 2 + sw, vdst + cc * 8192);
        }
    };

    stage_tiles(0, 0);
    __syncthreads();   // tile 0 ready

    for (int t = 0; t < 32; ++t) {
        const int pb = t & 1;
        unsigned char* const kbase = smem + KOFF + (unsigned)pb * 32768u;
        unsigned char* const vbase = smem + VOFF + (unsigned)pb * 32768u;

        if (t < 31) stage_tiles(t + 1, pb ^ 1);   // drains at end-of-iter barrier

        // ---- swapped QK^T: S^T[kv 32][q 32], A = K frag (LDS), B = Q frag (reg) ----
        f32x4 s[2][2];   // [m (kv16)][n (q16)]: [q = 16n + c][kv = 16m + 4g + r]
        s[0][0] = (f32x4)0.f; s[0][1] = (f32x4)0.f;
        s[1][0] = (f32x4)0.f; s[1][1] = (f32x4)0.f;
        __builtin_amdgcn_s_setprio(1);
        #pragma unroll
        for (int ks = 0; ks < 4; ++ks) {
            #pragma unroll
            for (int m = 0; m < 2; ++m) {
                f16x8 kf = *(const f16x8*)(kbase
                    + (unsigned)(wk * 32 + m * 16 + c) * 256u
                    + (unsigned)(((4 * ks + g) ^ (c & 7)) * 16));
                s[m][0] = __builtin_amdgcn_mfma_f32_16x16x32_f16(kf, qf[0][ks], s[m][0], 0, 0, 0);
                s[m][1] = __builtin_amdgcn_mfma_f32_16x16x32_f16(kf, qf[1][ks], s[m][1], 0, 0, 0);
            }
        }
        __builtin_amdgcn_s_setprio(0);

        // ---- V frags to registers now (port time hides under softmax) ----
        // PV B-frag (16x16x16): col d = 16df + c, k kv = 16m + 4g + i (i=0..3 -> 8B)
        f16x4 vr[2][8];
        #pragma unroll
        for (int df = 0; df < 8; ++df)
            #pragma unroll
            for (int m = 0; m < 2; ++m)
                vr[m][df] = *(const f16x4*)(vbase
                    + (unsigned)(df * 16 + c) * 256u
                    + (unsigned)((((4 * wk + 2 * m + (g >> 1)) ^ (c & 7)) * 16 + (g & 1) * 8)));

        // ---- lane-local softmax max (per q = 16n + c) ----
        float mt[2];
        #pragma unroll
        for (int n = 0; n < 2; ++n) {
            float a0 = fmaxf(fmaxf(s[0][n][0], s[0][n][1]), fmaxf(s[0][n][2], s[0][n][3]));
            float a1 = fmaxf(fmaxf(s[1][n][0], s[1][n][1]), fmaxf(s[1][n][2], s[1][n][3]));
            float v  = fmaxf(a0, a1);
            v = fmaxf(v, __shfl_xor(v, 16, 64));
            v = fmaxf(v, __shfl_xor(v, 32, 64));
            mt[n] = v;
        }

        bool need = (mt[0] > m_run[0] + DEFER_THR) || (mt[1] > m_run[1] + DEFER_THR);
        if (__any(need)) {
            float al[2];
            #pragma unroll
            for (int n = 0; n < 2; ++n) {
                float mn = fmaxf(m_run[n], mt[n]);
                al[n] = __builtin_amdgcn_exp2f(m_run[n] - mn);
                m_run[n] = mn;
                l_run[n] *= al[n];
            }
            float alo[2][4];
            #pragma unroll
            for (int n = 0; n < 2; ++n)
                #pragma unroll
                for (int r = 0; r < 4; ++r)
                    alo[n][r] = __shfl(al[n], 4 * g + r, 16);
            #pragma unroll
            for (int n = 0; n < 2; ++n)
                #pragma unroll
                for (int f = 0; f < 8; ++f)
                    #pragma unroll
                    for (int r = 0; r < 4; ++r) o[n][f][r] *= alo[n][r];
        }

        // e = exp2(S^T - m) in place; l accumulation via VALU + 2 shuffles
        #pragma unroll
        for (int m = 0; m < 2; ++m)
            #pragma unroll
            for (int n = 0; n < 2; ++n)
                #pragma unroll
                for (int r = 0; r < 4; ++r)
                    s[m][n][r] = __builtin_amdgcn_exp2f(s[m][n][r] - m_run[n]);

        #pragma unroll
        for (int n = 0; n < 2; ++n) {
            float ls = ((s[0][n][0] + s[0][n][1]) + (s[0][n][2] + s[0][n][3]))
                     + ((s[1][n][0] + s[1][n][1]) + (s[1][n][2] + s[1][n][3]));
            ls += __shfl_xor(ls, 16, 64);
            ls += __shfl_xor(ls, 32, 64);
            l_run[n] += ls;
        }

        // ---- P in-lane: pa[n][m] = f16x4 of s[m][n][0..3] (A-frag of 16x16x16 directly) ----
        f16x4 pa[2][2];
        #pragma unroll
        for (int n = 0; n < 2; ++n)
            #pragma unroll
            for (int m = 0; m < 2; ++m) {
                int2 wv;
                wv.x = __builtin_bit_cast(int, __builtin_amdgcn_cvt_pkrtz(s[m][n][0], s[m][n][1]));
                wv.y = __builtin_bit_cast(int, __builtin_amdgcn_cvt_pkrtz(s[m][n][2], s[m][n][3]));
                pa[n][m] = __builtin_bit_cast(f16x4, wv);
            }

        // ---- PV: O[32 q][128 d] += P[32 q][32 kv] * V[32 kv][128 d], K=16 MFMAs ----
        __builtin_amdgcn_s_setprio(1);
        #pragma unroll
        for (int df = 0; df < 8; ++df) {
            #pragma unroll
            for (int m = 0; m < 2; ++m) {
                o[0][df] = __builtin_amdgcn_mfma_f32_16x16x16f16(pa[0][m], vr[m][df], o[0][df], 0, 0, 0);
                o[1][df] = __builtin_amdgcn_mfma_f32_16x16x16f16(pa[1][m], vr[m][df], o[1][df], 0, 0, 0);
            }
        }
        __builtin_amdgcn_s_setprio(0);

        __syncthreads();   // this tile's reads done; next tile's staging drained
    }

    // ship m, l to O row domain (q = 16n + 4g + r)
    float m_o[2][4], l_o[2][4];
    #pragma unroll
    for (int n = 0; n < 2; ++n)
        #pragma unroll
        for (int r = 0; r < 4; ++r) {
            m_o[n][r] = __shfl(m_run[n], 4 * g + r, 16);
            l_o[n][r] = __shfl(l_run[n], 4 * g + r, 16);
        }

    float* const mld  = (float*)(smem + MOFF);
    float* const lld  = (float*)(smem + LOFF);
    float* const olds = (float*)smem;   // 64 rows x 132 f32, reuses K staging region

    if (c == 0) {
        #pragma unroll
        for (int n = 0; n < 2; ++n)
            #pragma unroll
            for (int r = 0; r < 4; ++r) {
                mld[w * 32 + n * 16 + 4 * g + r] = m_o[n][r];
                lld[w * 32 + n * 16 + 4 * g + r] = l_o[n][r];
            }
    }
    __syncthreads();

    float ms_s[2][4], lt_s[2][4];
    if (wk == 0) {
        #pragma unroll
        for (int n = 0; n < 2; ++n)
            #pragma unroll
            for (int r = 0; r < 4; ++r) {
                const int rl = n * 16 + 4 * g + r;
                float mm = m_o[n][r];
                #pragma unroll
                for (int i = 1; i < 4; ++i) mm = fmaxf(mm, mld[(wq * 4 + i) * 32 + rl]);
                ms_s[n][r] = mm;
                float a0 = __builtin_amdgcn_exp2f(m_o[n][r] - mm);
                float lt = a0 * l_o[n][r];
                #pragma unroll
                for (int i = 1; i < 4; ++i)
                    lt += __builtin_amdgcn_exp2f(mld[(wq * 4 + i) * 32 + rl] - mm)
                          * lld[(wq * 4 + i) * 32 + rl];
                lt_s[n][r] = lt;
                #pragma unroll
                for (int f = 0; f < 8; ++f) o[n][f][r] *= a0;
            }
    }

    // 3-phase accumulation through the 34 KB buffer
    for (int ph = 1; ph < 4; ++ph) {
        if (wk == ph) {
            #pragma unroll
            for (int n = 0; n < 2; ++n)
                #pragma unroll
                for (int f = 0; f < 8; ++f)
                    #pragma unroll
                    for (int r = 0; r < 4; ++r)
                        olds[(size_t)(wq * 32 + n * 16 + 4 * g + r) * 132 + f * 16 + c] = o[n][f][r];
        }
        __syncthreads();
        if (wk == 0) {
            #pragma unroll
            for (int n = 0; n < 2; ++n)
                #pragma unroll
                for (int r = 0; r < 4; ++r) {
                    const int rl = n * 16 + 4 * g + r;
                    const float ai = __builtin_amdgcn_exp2f(mld[(wq * 4 + ph) * 32 + rl] - ms_s[n][r]);
                    #pragma unroll
                    for (int f = 0; f < 8; ++f)
                        o[n][f][r] += ai * olds[(size_t)(wq * 32 + rl) * 132 + f * 16 + c];
                }
        }
        __syncthreads();
    }

    if (wk == 0) {
        #pragma unroll
        for (int n = 0; n < 2; ++n)
            #pragma unroll
            for (int r = 0; r < 4; ++r) {
                const int rl = n * 16 + 4 * g + r;
                const int q  = q0 + wq * 32 + rl;
                const float inv = 1.0f / lt_s[n][r];
                float* orow = out + ((size_t)bb * SEQ + q) * DQK;
                #pragma unroll
                for (int f = 0; f < 8; ++f)
                    orow[f * 16 + c] = o[n][f][r] * inv;
            }
    }
}

extern "C" void kernel_launch(void* const* d_in, const int* in_sizes, int n_in,
                              void* d_out, int out_size, void* d_ws, size_t ws_size,
                              hipStream_t stream) {
    const float* x  = (const float*)d_in[0];
    const float* Wq = (const float*)d_in[1];
    const float* bq = (const float*)d_in[2];
    const float* Wk = (const float*)d_in[3];
    const float* bk = (const float*)d_in[4];
    const float* Wv = (const float*)d_in[5];
    const float* bv = (const float*)d_in[6];
    float* outp = (float*)d_out;

    f16*   qf    = (f16*)d_ws;
    f16*   kf    = qf + (size_t)BATCH * SEQ * DQK;
    f16*   vt    = kf + (size_t)BATCH * SEQ * DQK;
    f16*   wt    = vt + (size_t)BATCH * DQK * SEQ;
    float* biasf = (float*)(wt + (size_t)384 * DM);

    wcvt_kernel<<<24, 256, 0, stream>>>(Wq, bq, Wk, bk, Wv, bv, wt, biasf);

    proj_kernel<<<BATCH * SEQ / 64, 512, 0, stream>>>(x, wt, biasf, qf, kf, vt);

    attn_kernel<<<256, 512, 0, stream>>>(qf, kf, vt, outp);
}

// Round 11
// 92.116 us; speedup vs baseline: 1.2086x; 1.2086x over previous
//
#include <hip/hip_runtime.h>
#include <math.h>

#define DM    1024
#define DQK   128
#define BATCH 4
#define SEQ   4096
// 1/sqrt(128) * log2(e) folded into Wq/bq at wcvt time -> softmax uses exp2 directly
#define QSCALE (0.08838834764831845f * 1.4426950408889634f)
#define DEFER_THR 6.0f

typedef _Float16 f16;
typedef _Float16 f16x4 __attribute__((ext_vector_type(4)));
typedef _Float16 f16x8 __attribute__((ext_vector_type(8)));
typedef float    f32x4 __attribute__((ext_vector_type(4)));

__device__ __forceinline__ void stage16(const void* g, unsigned char* l) {
    __builtin_amdgcn_global_load_lds(
        (const __attribute__((address_space(1))) unsigned int*)g,
        (__attribute__((address_space(3))) unsigned int*)l, 16, 0, 0);
}

// ---------------- W convert/transpose pre-kernel (unchanged) ----------------
__global__ __launch_bounds__(256) void wcvt_kernel(
    const float* __restrict__ Wq, const float* __restrict__ bq,
    const float* __restrict__ Wk, const float* __restrict__ bk,
    const float* __restrict__ Wv, const float* __restrict__ bv,
    f16* __restrict__ wt, float* __restrict__ biasf)
{
    const int sel = blockIdx.x >> 3;
    const int k0  = (blockIdx.x & 7) * 128;
    const float* W; const float* b; float sc;
    if (sel == 0)      { W = Wq; b = bq; sc = QSCALE; }
    else if (sel == 1) { W = Wk; b = bk; sc = 1.0f; }
    else               { W = Wv; b = bv; sc = 1.0f; }

    __shared__ f16 tile[128][136];

    #pragma unroll
    for (int it = 0; it < 16; ++it) {
        int flat = threadIdx.x + it * 256;
        int kk   = flat >> 5;
        int c4   = flat & 31;
        float4 w4 = *(const float4*)(W + (size_t)(k0 + kk) * DQK + c4 * 4);
        tile[kk][c4 * 4 + 0] = (f16)(w4.x * sc);
        tile[kk][c4 * 4 + 1] = (f16)(w4.y * sc);
        tile[kk][c4 * 4 + 2] = (f16)(w4.z * sc);
        tile[kk][c4 * 4 + 3] = (f16)(w4.w * sc);
    }
    __syncthreads();

    #pragma unroll
    for (int it = 0; it < 8; ++it) {
        int flat = threadIdx.x + it * 256;
        int n    = flat >> 4;
        int kc   = flat & 15;
        f16x8 v;
        #pragma unroll
        for (int i = 0; i < 8; ++i) v[i] = tile[kc * 8 + i][n];
        *(f16x8*)(wt + (size_t)(sel * 128 + n) * DM + k0 + kc * 8) = v;
    }
    if ((blockIdx.x & 7) == 0 && threadIdx.x < 128)
        biasf[sel * 128 + threadIdx.x] = b[threadIdx.x] * sc;
}

// ---------------- Fused QKV projection: W k-slice staged in LDS ----------------
// 256 blocks x 512 thr. Block: 64 rows x 384 cols. Wave w: 64 rows x 48 cols.
// Per iter t (k-chunk of 64): x [64][64] f16 reg-staged dbuf (as before) + W slice
// [384 n][64 k] f16 (48 KB) via global_load_lds dbuf, XOR-swizzled through pre-swizzled
// global source. B-frags now ds_read_b128 (attn-K-tile geometry) instead of scattered
// global loads. One barrier/iter (r4-attn schedule). LDS 112 KB -> 1 block/CU.
#define PXOFF 0u        // 2 x 8 KB x double buffer
#define PWOFF 16384u    // 2 x 48 KB W double buffer

__global__ __launch_bounds__(512, 2) void proj_kernel(
    const float* __restrict__ x, const f16* __restrict__ wt,
    const float* __restrict__ biasf,
    f16* __restrict__ qo, f16* __restrict__ ko, f16* __restrict__ vto)
{
    __shared__ __align__(16) unsigned char smem[114688];

    const int tid  = threadIdx.x;
    const int lane = tid & 63;
    const int w    = tid >> 6;
    const int c    = lane & 15;
    const int g    = lane >> 4;
    const int r0   = blockIdx.x * 64;

    // x staging role: thread -> (row, 8-f16 chunk)
    const int srow = tid >> 3;
    const int skq  = tid & 7;
    const float* const xsrc  = x + (size_t)(r0 + srow) * DM + skq * 8;
    const unsigned     swoff = (unsigned)(srow * 128 + ((skq ^ (srow & 7)) * 16));

    // W staging role: per (cc): chunk j = tid + cc*512; n = j>>3, kc = lane&7
    const char* const wtB   = (const char*)wt;
    const unsigned    wsrcsw = (unsigned)(((lane & 7) ^ ((lane >> 3) & 7)) * 16);

    f32x4 acc[4][3];
    #pragma unroll
    for (int rf = 0; rf < 4; ++rf)
        #pragma unroll
        for (int nf = 0; nf < 3; ++nf) acc[rf][nf] = (f32x4)0.f;

    float4 xa, xb2;
    auto gload = [&](int t) {
        const float* p = xsrc + t * 64;
        xa  = *(const float4*)p;
        xb2 = *(const float4*)(p + 4);
    };
    auto swrite = [&](int buf) {
        f16x8 h;
        h[0] = (f16)xa.x;  h[1] = (f16)xa.y;  h[2] = (f16)xa.z;  h[3] = (f16)xa.w;
        h[4] = (f16)xb2.x; h[5] = (f16)xb2.y; h[6] = (f16)xb2.z; h[7] = (f16)xb2.w;
        *(f16x8*)(smem + PXOFF + (unsigned)buf * 8192u + swoff) = h;
    };
    auto stage_W = [&](int t, int pbuf) {
        unsigned char* wdst = smem + PWOFF + (unsigned)pbuf * 49152u + (unsigned)w * 1024u;
        #pragma unroll
        for (int cc = 0; cc < 6; ++cc) {
            const int j = tid + cc * 512;       // 0..3071
            const int n = j >> 3;               // 0..383
            stage16(wtB + (size_t)n * 2048 + (size_t)t * 128 + wsrcsw, wdst + cc * 8192);
        }
    };

    gload(0); swrite(0);
    gload(1);
    stage_W(0, 0);
    __syncthreads();   // x(0) visible, W(0) drained

    for (int t = 0; t < 16; ++t) {
        const int cur = t & 1;
        if (t < 15) swrite(cur ^ 1);          // x(t+1), loaded last iter
        if (t < 14) gload(t + 2);             // x prefetch 2 ahead
        if (t < 15) stage_W(t + 1, cur ^ 1);  // W(t+1), drains at end-of-iter barrier

        // A-frags from swizzled x LDS: row = rf*16+c, k = ks*32 + g*8
        f16x8 af[4][2];
        #pragma unroll
        for (int rf = 0; rf < 4; ++rf)
            #pragma unroll
            for (int ks = 0; ks < 2; ++ks)
                af[rf][ks] = *(const f16x8*)(smem + PXOFF + (unsigned)cur * 8192u
                    + (unsigned)((rf * 16 + c) * 128)
                    + (unsigned)((((4 * ks + g) ^ (c & 7)) * 16)));

        // B-frags from swizzled W LDS: n = w*48 + nf*16 + c, kc = ks*4 + g
        unsigned char* const wbase = smem + PWOFF + (unsigned)cur * 49152u;
        #pragma unroll
        for (int nf = 0; nf < 3; ++nf) {
            #pragma unroll
            for (int ks = 0; ks < 2; ++ks) {
                f16x8 bf = *(const f16x8*)(wbase
                    + (unsigned)((w * 48 + nf * 16 + c) * 128)
                    + (unsigned)((((4 * ks + g) ^ (c & 7)) * 16)));
                #pragma unroll
                for (int rf = 0; rf < 4; ++rf)
                    acc[rf][nf] = __builtin_amdgcn_mfma_f32_16x16x32_f16(
                        af[rf][ks], bf, acc[rf][nf], 0, 0, 0);
            }
        }
        __syncthreads();
    }

    // ---- epilogue: bias + f16, bounce through LDS tile [64][392] for coalesced stores ----
    f16* const tile = (f16*)smem;
    #pragma unroll
    for (int rf = 0; rf < 4; ++rf)
        #pragma unroll
        for (int nf = 0; nf < 3; ++nf) {
            const int n  = w * 48 + nf * 16 + c;
            const float bb = biasf[n];
            #pragma unroll
            for (int r = 0; r < 4; ++r) {
                const int row = rf * 16 + 4 * g + r;
                tile[row * 392 + n] = (f16)(acc[rf][nf][r] + bb);
            }
        }
    __syncthreads();

    #pragma unroll
    for (int it = 0; it < 2; ++it) {
        const int u   = tid + it * 512;
        const int row = u >> 4;
        const int c8  = (u & 15) * 8;
        *(f16x8*)(qo + (size_t)(r0 + row) * DQK + c8) = *(const f16x8*)&tile[row * 392 + c8];
        *(f16x8*)(ko + (size_t)(r0 + row) * DQK + c8) = *(const f16x8*)&tile[row * 392 + 128 + c8];
    }
    const int gb = r0 >> 12;
    const int s0 = r0 & (SEQ - 1);
    #pragma unroll
    for (int it = 0; it < 2; ++it) {
        const int u  = tid + it * 512;
        const int d  = u >> 3;
        const int s8 = (u & 7) * 8;
        f16x8 vv;
        #pragma unroll
        for (int i = 0; i < 8; ++i) vv[i] = tile[(s8 + i) * 392 + 256 + d];
        *(f16x8*)(vto + ((size_t)gb * DQK + d) * SEQ + s0 + s8) = vv;
    }
}

// ---------------- Flash attention: EXACT round-4 winner (66 us) ----------------
#define KOFF 0u
#define VOFF 65536u
#define POFF 131072u
#define MOFF 151552u
#define LOFF 152576u

__global__ __launch_bounds__(512, 2) void attn_kernel(
    const f16* __restrict__ qg, const f16* __restrict__ kg,
    const f16* __restrict__ vtg, float* __restrict__ out)
{
    __shared__ __align__(16) unsigned char smem[153600];

    const int tid  = threadIdx.x;
    const int lane = tid & 63;
    const int w    = tid >> 6;      // 0..7
    const int wq   = w >> 2;        // 0..1
    const int wk   = w & 3;         // 0..3
    const int c    = lane & 15;
    const int g    = lane >> 4;     // 0..3

    const int bid = blockIdx.x;
    const int xcd = bid & 7;
    const int bb  = xcd >> 1;
    const int qt  = (bid >> 3) | ((xcd & 1) << 5);
    const int q0  = qt * 64;

    const f16*  qb = qg  + (size_t)bb * SEQ * DQK;
    const char* kB = (const char*)(kg  + (size_t)bb * SEQ * DQK);
    const char* vB = (const char*)(vtg + (size_t)bb * DQK * SEQ);

    // Q frags (B-operand for swapped QK^T): q = 16n + c, k(d) = ks*32 + 8g + i
    f16x8 qf[2][4];
    {
        const f16* qr = qb + (size_t)(q0 + wq * 32) * DQK;
        #pragma unroll
        for (int n = 0; n < 2; ++n)
            #pragma unroll
            for (int ks = 0; ks < 4; ++ks)
                qf[n][ks] = *(const f16x8*)(qr + (n * 16 + c) * DQK + ks * 32 + 8 * g);
    }

    f32x4 o[2][9];   // [n (q-frag)][d-frag 0..7, 8 = ones column = running l]
    #pragma unroll
    for (int n = 0; n < 2; ++n)
        #pragma unroll
        for (int f = 0; f < 9; ++f) o[n][f] = (f32x4)0.f;
    float m_run[2] = {-3e38f, -3e38f};   // S^T domain: q = 16n + c

    f16x8 onesf;
    #pragma unroll
    for (int i = 0; i < 8; ++i) onesf[i] = (f16)1.0f;

    const unsigned wbase = (unsigned)(tid >> 6) * 1024;

    auto stage_tiles = [&](int t, int pbuf) {
        const int kv0 = t * 128;
        unsigned char* kdst = smem + KOFF + (unsigned)pbuf * 32768u + wbase;
        unsigned char* vdst = smem + VOFF + (unsigned)pbuf * 32768u + wbase;
        #pragma unroll
        for (int cc = 0; cc < 4; ++cc) {
            const int j   = tid + cc * 512;
            const int row = j >> 4;
            const int col = j & 15;
            const int sw  = (col ^ (row & 7)) * 16;
            stage16(kB + (size_t)(kv0 + row) * 256 + sw, kdst + cc * 8192);
            stage16(vB + (size_t)row * 8192 + (size_t)kv0 * 2 + sw, vdst + cc * 8192);
        }
    };

    stage_tiles(0, 0);
    __syncthreads();

    unsigned char* const pmine = smem + POFF + (unsigned)w * 2560u;

    for (int t = 0; t < 32; ++t) {
        const int pb = t & 1;
        if (t < 31) stage_tiles(t + 1, pb ^ 1);

        unsigned char* const kbase = smem + KOFF + (unsigned)pb * 32768u;
        unsigned char* const vbase = smem + VOFF + (unsigned)pb * 32768u;

        // ---- swapped QK^T: S^T[kv 32][q 32] per wave ----
        f32x4 s[2][2];   // [m (kv16)][n (q16)]
        s[0][0] = (f32x4)0.f; s[0][1] = (f32x4)0.f;
        s[1][0] = (f32x4)0.f; s[1][1] = (f32x4)0.f;
        __builtin_amdgcn_s_setprio(1);
        #pragma unroll
        for (int ks = 0; ks < 4; ++ks) {
            #pragma unroll
            for (int m = 0; m < 2; ++m) {
                f16x8 kf = *(const f16x8*)(kbase
                    + (unsigned)(wk * 32 + m * 16 + c) * 256u
                    + (unsigned)(((4 * ks + g) ^ (c & 7)) * 16));
                s[m][0] = __builtin_amdgcn_mfma_f32_16x16x32_f16(kf, qf[0][ks], s[m][0], 0, 0, 0);
                s[m][1] = __builtin_amdgcn_mfma_f32_16x16x32_f16(kf, qf[1][ks], s[m][1], 0, 0, 0);
            }
        }
        __builtin_amdgcn_s_setprio(0);

        // ---- lane-local softmax max (per q-row = 16n + c) ----
        float mt[2];
        #pragma unroll
        for (int n = 0; n < 2; ++n) {
            float a0 = fmaxf(fmaxf(s[0][n][0], s[0][n][1]), fmaxf(s[0][n][2], s[0][n][3]));
            float a1 = fmaxf(fmaxf(s[1][n][0], s[1][n][1]), fmaxf(s[1][n][2], s[1][n][3]));
            float v  = fmaxf(a0, a1);
            v = fmaxf(v, __shfl_xor(v, 16, 64));
            v = fmaxf(v, __shfl_xor(v, 32, 64));
            mt[n] = v;
        }

        // ---- defer-max: rescale only when the running max grows past THR ----
        bool need = (mt[0] > m_run[0] + DEFER_THR) || (mt[1] > m_run[1] + DEFER_THR);
        if (__any(need)) {
            float al[2];
            #pragma unroll
            for (int n = 0; n < 2; ++n) {
                float mn = fmaxf(m_run[n], mt[n]);
                al[n] = __builtin_amdgcn_exp2f(m_run[n] - mn);
                m_run[n] = mn;
            }
            float alo[2][4];
            #pragma unroll
            for (int n = 0; n < 2; ++n)
                #pragma unroll
                for (int r = 0; r < 4; ++r)
                    alo[n][r] = __shfl(al[n], 4 * g + r, 16);
            #pragma unroll
            for (int n = 0; n < 2; ++n)
                #pragma unroll
                for (int f = 0; f < 9; ++f)
                    #pragma unroll
                    for (int r = 0; r < 4; ++r) o[n][f][r] *= alo[n][r];
        }

        // ---- P = exp2(S^T - m), packed b64 stores: P[q = 16n+c][kv = 16m+4g .. +3] ----
        #pragma unroll
        for (int n = 0; n < 2; ++n)
            #pragma unroll
            for (int m = 0; m < 2; ++m) {
                f16x4 h;
                #pragma unroll
                for (int r = 0; r < 4; ++r)
                    h[r] = (f16)__builtin_amdgcn_exp2f(s[m][n][r] - m_run[n]);
                *(f16x4*)(pmine + (unsigned)(16 * n + c) * 80u + (unsigned)(32 * m + 8 * g)) = h;
            }

        // ---- PV: O[32 q][128 d] += P[32 q][32 kv] * V[32 kv][128 d] ----
        f16x8 pa[2];
        pa[0] = *(const f16x8*)(pmine + (unsigned)(c) * 80u + 16u * g);
        pa[1] = *(const f16x8*)(pmine + (unsigned)(16 + c) * 80u + 16u * g);
        __builtin_amdgcn_s_setprio(1);
        #pragma unroll
        for (int df = 0; df < 8; ++df) {
            f16x8 vf = *(const f16x8*)(vbase
                + (unsigned)(df * 16 + c) * 256u
                + (unsigned)(((4 * wk + g) ^ (c & 7)) * 16));
            o[0][df] = __builtin_amdgcn_mfma_f32_16x16x32_f16(pa[0], vf, o[0][df], 0, 0, 0);
            o[1][df] = __builtin_amdgcn_mfma_f32_16x16x32_f16(pa[1], vf, o[1][df], 0, 0, 0);
        }
        o[0][8] = __builtin_amdgcn_mfma_f32_16x16x32_f16(pa[0], onesf, o[0][8], 0, 0, 0);
        o[1][8] = __builtin_amdgcn_mfma_f32_16x16x32_f16(pa[1], onesf, o[1][8], 0, 0, 0);
        __builtin_amdgcn_s_setprio(0);

        __syncthreads();
    }

    // ship final m to O domain (q = 16n + 4g + r)
    float m_o[2][4];
    #pragma unroll
    for (int n = 0; n < 2; ++n)
        #pragma unroll
        for (int r = 0; r < 4; ++r)
            m_o[n][r] = __shfl(m_run[n], 4 * g + r, 16);

    // ---- merge the 4 kv-splits (per wq) via LDS ----
    float* const mld  = (float*)(smem + MOFF);
    float* const lld  = (float*)(smem + LOFF);
    float* const olds = (float*)smem;

    if (wk > 0) {
        const int base = (wq * 3 + (wk - 1)) * 32;
        #pragma unroll
        for (int n = 0; n < 2; ++n)
            #pragma unroll
            for (int f = 0; f < 8; ++f)
                #pragma unroll
                for (int r = 0; r < 4; ++r)
                    olds[(size_t)(base + n * 16 + 4 * g + r) * 132 + f * 16 + c] = o[n][f][r];
        if (c == 0) {
            #pragma unroll
            for (int n = 0; n < 2; ++n)
                #pragma unroll
                for (int r = 0; r < 4; ++r) {
                    mld[(wq * 4 + wk) * 32 + n * 16 + 4 * g + r] = m_o[n][r];
                    lld[(wq * 4 + wk) * 32 + n * 16 + 4 * g + r] = o[n][8][r];
                }
        }
    }
    __syncthreads();

    if (wk == 0) {
        #pragma unroll
        for (int n = 0; n < 2; ++n) {
            #pragma unroll
            for (int r = 0; r < 4; ++r) {
                const int rl = n * 16 + 4 * g + r;
                const float m0 = m_o[n][r];
                const float m1 = mld[(wq * 4 + 1) * 32 + rl];
                const float m2 = mld[(wq * 4 + 2) * 32 + rl];
                const float m3 = mld[(wq * 4 + 3) * 32 + rl];
                const float ms = fmaxf(fmaxf(m0, m1), fmaxf(m2, m3));
                const float a0 = __builtin_amdgcn_exp2f(m0 - ms);
                const float a1 = __builtin_amdgcn_exp2f(m1 - ms);
                const float a2 = __builtin_amdgcn_exp2f(m2 - ms);
                const float a3 = __builtin_amdgcn_exp2f(m3 - ms);
                const float ls = a0 * o[n][8][r]
                               + a1 * lld[(wq * 4 + 1) * 32 + rl]
                               + a2 * lld[(wq * 4 + 2) * 32 + rl]
                               + a3 * lld[(wq * 4 + 3) * 32 + rl];
                const float inv = 1.0f / ls;
                float* orow = out + ((size_t)bb * SEQ + q0 + wq * 32 + rl) * DQK;
                #pragma unroll
                for (int f = 0; f < 8; ++f) {
                    float v = a0 * o[n][f][r]
                            + a1 * olds[(size_t)((wq * 3 + 0) * 32 + rl) * 132 + f * 16 + c]
                            + a2 * olds[(size_t)((wq * 3 + 1) * 32 + rl) * 132 + f * 16 + c]
                            + a3 * olds[(size_t)((wq * 3 + 2) * 32 + rl) * 132 + f * 16 + c];
                    orow[f * 16 + c] = v * inv;
                }
            }
        }
    }
}

extern "C" void kernel_launch(void* const* d_in, const int* in_sizes, int n_in,
                              void* d_out, int out_size, void* d_ws, size_t ws_size,
                              hipStream_t stream) {
    const float* x  = (const float*)d_in[0];
    const float* Wq = (const float*)d_in[1];
    const float* bq = (const float*)d_in[2];
    const float* Wk = (const float*)d_in[3];
    const float* bk = (const float*)d_in[4];
    const float* Wv = (const float*)d_in[5];
    const float* bv = (const float*)d_in[6];
    float* outp = (float*)d_out;

    f16*   qf    = (f16*)d_ws;
    f16*   kf    = qf + (size_t)BATCH * SEQ * DQK;
    f16*   vt    = kf + (size_t)BATCH * SEQ * DQK;
    f16*   wt    = vt + (size_t)BATCH * DQK * SEQ;
    float* biasf = (float*)(wt + (size_t)384 * DM);

    wcvt_kernel<<<24, 256, 0, stream>>>(Wq, bq, Wk, bk, Wv, bv, wt, biasf);

    proj_kernel<<<BATCH * SEQ / 64, 512, 0, stream>>>(x, wt, biasf, qf, kf, vt);

    attn_kernel<<<256, 512, 0, stream>>>(qf, kf, vt, outp);
}